// Round 1
// baseline (12012.096 us; speedup 1.0000x reference)
//
#include <hip/hip_runtime.h>
#include <hip/hip_bf16.h>

typedef __hip_bfloat16 bf16;
typedef __bf16 bf16x8 __attribute__((ext_vector_type(8)));
typedef float f32x4 __attribute__((ext_vector_type(4)));

#define B_      256
#define S_      128
#define HID_    768
#define EMB_    128
#define FF_     3072
#define LAYERS_ 12
#define HEADS_  12
#define DH_     64
#define M_TOK   (B_ * S_)   // 32768

__device__ inline float b2f(bf16 v) { return __bfloat162float(v); }
__device__ inline bf16  f2b(float v) { return __float2bfloat16(v); }

__device__ inline float wave_sum(float v) {
#pragma unroll
  for (int o = 32; o > 0; o >>= 1) v += __shfl_xor(v, o, 64);
  return v;
}

__device__ inline float gelu_exact(float x) {
  return 0.5f * x * (1.0f + erff(x * 0.70710678118654752f));
}

__device__ inline void glds16(const bf16* g, bf16* l) {
  __builtin_amdgcn_global_load_lds(
      (const __attribute__((address_space(1))) void*)g,
      (__attribute__((address_space(3))) void*)l, 16, 0, 0);
}

// ---------------------------------------------------------------------------
// C = A (MxK, bf16 rm) * Bt^T (Bt is NxK, bf16 rm) + bias; mode 0: bias,
// mode 1: bias+gelu, mode 2: bias+gelu+posenc.  M%128==0, N%128==0, K%32==0.
// ---------------------------------------------------------------------------
__global__ __launch_bounds__(256)
void gemm_bt(const bf16* __restrict__ A, const bf16* __restrict__ Bt,
             const float* __restrict__ bias, bf16* __restrict__ C,
             int M, int N, int K, int mode)
{
  __shared__ __align__(16) bf16 As[128 * 32];
  __shared__ __align__(16) bf16 Bs[128 * 32];
  const int tid  = threadIdx.x;
  const int wave = tid >> 6, lane = tid & 63;
  const int m0 = blockIdx.y * 128, n0 = blockIdx.x * 128;

  // staging: 8 chunks of 1KB (16 rows x 32 cols) per tile; wave w owns chunks 2w,2w+1
  const int ar = lane >> 2;         // row within chunk
  const int ac = (lane & 3) * 8;    // col (elements)
  const int c0 = wave * 2;
  const bf16* ga0 = A  + (size_t)(m0 + c0 * 16      + ar) * K + ac;
  const bf16* ga1 = A  + (size_t)(m0 + (c0+1) * 16  + ar) * K + ac;
  const bf16* gb0 = Bt + (size_t)(n0 + c0 * 16      + ar) * K + ac;
  const bf16* gb1 = Bt + (size_t)(n0 + (c0+1) * 16  + ar) * K + ac;
  bf16* lA0 = As + c0 * 512;       bf16* lA1 = As + (c0 + 1) * 512;
  bf16* lB0 = Bs + c0 * 512;       bf16* lB1 = Bs + (c0 + 1) * 512;

  const int lr = lane & 15;
  const int lk = (lane >> 4) * 8;
  const int rm = (wave >> 1) * 64;
  const int rn = (wave & 1) * 64;

  const f32x4 zacc = {0.f, 0.f, 0.f, 0.f};
  f32x4 acc[4][4];
#pragma unroll
  for (int i = 0; i < 4; i++)
#pragma unroll
    for (int j = 0; j < 4; j++) acc[i][j] = zacc;

  for (int k0 = 0; k0 < K; k0 += 32) {
    glds16(ga0 + k0, lA0);
    glds16(ga1 + k0, lA1);
    glds16(gb0 + k0, lB0);
    glds16(gb1 + k0, lB1);
    __syncthreads();
    bf16x8 af[4], bfr[4];
#pragma unroll
    for (int i = 0; i < 4; i++) af[i]  = *(const bf16x8*)&As[(rm + i * 16 + lr) * 32 + lk];
#pragma unroll
    for (int j = 0; j < 4; j++) bfr[j] = *(const bf16x8*)&Bs[(rn + j * 16 + lr) * 32 + lk];
#pragma unroll
    for (int i = 0; i < 4; i++)
#pragma unroll
      for (int j = 0; j < 4; j++)
        acc[i][j] = __builtin_amdgcn_mfma_f32_16x16x32_bf16(af[i], bfr[j], acc[i][j], 0, 0, 0);
    __syncthreads();
  }

  // epilogue: D[row][col], col = lane&15, row = (lane>>4)*4 + reg
  const int er = (lane >> 4) * 4;
  const int ec = lane & 15;
#pragma unroll
  for (int i = 0; i < 4; i++) {
    const int row = m0 + rm + i * 16 + er;
#pragma unroll
    for (int j = 0; j < 4; j++) {
      const int col = n0 + rn + j * 16 + ec;
      const float bv = bias[col];
#pragma unroll
      for (int r = 0; r < 4; r++) {
        float v = acc[i][j][r] + bv;
        if (mode >= 1) v = gelu_exact(v);
        if (mode == 2) {
          const int srow = (row + r) & (S_ - 1);
          const int i2 = col & ~1;
          const float div = expf(-9.210340371976184f * (float)i2 * (1.0f / (float)HID_));
          const float ang = (float)srow * div;
          v += (col & 1) ? cosf(ang) : sinf(ang);
        }
        C[(size_t)(row + r) * N + col] = f2b(v);
      }
    }
  }
}

// ---------------------------------------------------------------------------
// fp32 (K,N) -> bf16 (N,K) convert + transpose.  K%32==0, N%32==0. block (32,8)
// ---------------------------------------------------------------------------
__global__ __launch_bounds__(256)
void convtrans(const float* __restrict__ src, bf16* __restrict__ dst, int K, int N)
{
  __shared__ bf16 t[32][33];
  const int n0 = blockIdx.x * 32, k0 = blockIdx.y * 32;
  const int tx = threadIdx.x, ty = threadIdx.y;
#pragma unroll
  for (int i = 0; i < 4; i++)
    t[ty + i * 8][tx] = f2b(src[(size_t)(k0 + ty + i * 8) * N + n0 + tx]);
  __syncthreads();
#pragma unroll
  for (int i = 0; i < 4; i++)
    dst[(size_t)(n0 + ty + i * 8) * K + k0 + tx] = t[tx][ty + i * 8];
}

// ---------------------------------------------------------------------------
// sliding-window attention: one block per (b, head), 128 threads (one per row)
// ---------------------------------------------------------------------------
__global__ __launch_bounds__(128)
void attn_kernel(const bf16* __restrict__ qkv, bf16* __restrict__ ctx)
{
  const int bh = blockIdx.x;
  const int b = bh / HEADS_, h = bh % HEADS_;
  __shared__ __align__(16) bf16 qs[S_ * DH_];
  __shared__ __align__(16) bf16 ks[S_ * DH_];
  __shared__ __align__(16) bf16 vs[S_ * DH_];
  const int tid = threadIdx.x;
  const bf16* base = qkv + (size_t)b * S_ * (3 * HID_) + h * DH_;
  for (int it = 0; it < 8; ++it) {
    const int s = it * 16 + (tid >> 3);
    const int seg = (tid & 7) * 8;
    const size_t go = (size_t)s * (3 * HID_) + seg;
    *(uint4*)&qs[s * DH_ + seg] = *(const uint4*)&base[go];
    *(uint4*)&ks[s * DH_ + seg] = *(const uint4*)&base[go + HID_];
    *(uint4*)&vs[s * DH_ + seg] = *(const uint4*)&base[go + 2 * HID_];
  }
  __syncthreads();
  const int i = tid;
  bf16* out = ctx + (size_t)(b * S_ + i) * HID_ + h * DH_;
  if (i < 116) {
    float p[13];
    float mx = -1e30f;
    for (int jj = 0; jj < 13; jj++) {
      if (jj == 6) { p[jj] = 0.f; continue; }
      float d = 0.f;
#pragma unroll
      for (int dd = 0; dd < DH_; dd++) d += b2f(qs[i * DH_ + dd]) * b2f(ks[(i + jj) * DH_ + dd]);
      p[jj] = d * 0.125f;
      mx = fmaxf(mx, p[jj]);
    }
    float l = 0.f;
    for (int jj = 0; jj < 13; jj++) {
      if (jj == 6) { p[jj] = 0.f; continue; }
      p[jj] = expf(p[jj] - mx);
      l += p[jj];
    }
    const float inv = 1.f / l;
    float o[DH_];
#pragma unroll
    for (int dd = 0; dd < DH_; dd++) o[dd] = 0.f;
    for (int jj = 0; jj < 13; jj++) {
      if (jj == 6) continue;
      const float pj = p[jj] * inv;
#pragma unroll
      for (int dd = 0; dd < DH_; dd++) o[dd] += pj * b2f(vs[(i + jj) * DH_ + dd]);
    }
#pragma unroll
    for (int dd = 0; dd < DH_; dd++) out[dd] = f2b(o[dd]);
  } else {
#pragma unroll
    for (int dd = 0; dd < DH_; dd++) out[dd] = f2b(0.f);
  }
}

// ---------------------------------------------------------------------------
// out = LN(x + y) over 768, bf16 in/out, fp32 math.  one block per row.
// ---------------------------------------------------------------------------
__global__ __launch_bounds__(256)
void add_ln_kernel(const bf16* __restrict__ x, const bf16* __restrict__ y,
                   const float* __restrict__ g, const float* __restrict__ bta,
                   bf16* __restrict__ out)
{
  const int r = blockIdx.x, tid = threadIdx.x;
  const size_t base = (size_t)r * HID_;
  float v[3];
#pragma unroll
  for (int e = 0; e < 3; e++) {
    const int idx = tid + e * 256;
    v[e] = b2f(x[base + idx]) + b2f(y[base + idx]);
  }
  float s  = v[0] + v[1] + v[2];
  float ss = v[0] * v[0] + v[1] * v[1] + v[2] * v[2];
  s = wave_sum(s);
  ss = wave_sum(ss);
  __shared__ float red[8];
  const int wave = tid >> 6, lane = tid & 63;
  if (lane == 0) { red[wave] = s; red[4 + wave] = ss; }
  __syncthreads();
  s  = red[0] + red[1] + red[2] + red[3];
  ss = red[4] + red[5] + red[6] + red[7];
  const float mean = s * (1.f / (float)HID_);
  const float var  = ss * (1.f / (float)HID_) - mean * mean;
  const float rs = rsqrtf(var + 1e-5f);
#pragma unroll
  for (int e = 0; e < 3; e++) {
    const int idx = tid + e * 256;
    out[base + idx] = f2b((v[e] - mean) * rs * g[idx] + bta[idx]);
  }
}

// ---------------------------------------------------------------------------
// out[token] = LN(W[idx[token]]) over 128.  one wave per token, 4 tokens/block
// ---------------------------------------------------------------------------
__global__ __launch_bounds__(256)
void gather_ln128(const int* __restrict__ idx, const float* __restrict__ W,
                  const float* __restrict__ g, const float* __restrict__ bta,
                  bf16* __restrict__ out)
{
  const int token = blockIdx.x * 4 + (threadIdx.x >> 6);
  const int lane = threadIdx.x & 63;
  const int row = idx[token];
  const float* src = W + (size_t)row * 128;
  const float a = src[lane], c = src[lane + 64];
  const float s  = wave_sum(a + c);
  const float ss = wave_sum(a * a + c * c);
  const float mean = s * (1.f / 128.f);
  const float var  = ss * (1.f / 128.f) - mean * mean;
  const float rs = rsqrtf(var + 1e-5f);
  bf16* o = out + (size_t)token * 128;
  o[lane]      = f2b((a - mean) * rs * g[lane] + bta[lane]);
  o[lane + 64] = f2b((c - mean) * rs * g[lane + 64] + bta[lane + 64]);
}

__global__ __launch_bounds__(256)
void ln128_bf16(const bf16* __restrict__ in, const float* __restrict__ g,
                const float* __restrict__ bta, bf16* __restrict__ out)
{
  const int token = blockIdx.x * 4 + (threadIdx.x >> 6);
  const int lane = threadIdx.x & 63;
  const bf16* src = in + (size_t)token * 128;
  const float a = b2f(src[lane]), c = b2f(src[lane + 64]);
  const float s  = wave_sum(a + c);
  const float ss = wave_sum(a * a + c * c);
  const float mean = s * (1.f / 128.f);
  const float var  = ss * (1.f / 128.f) - mean * mean;
  const float rs = rsqrtf(var + 1e-5f);
  bf16* o = out + (size_t)token * 128;
  o[lane]      = f2b((a - mean) * rs * g[lane] + bta[lane]);
  o[lane + 64] = f2b((c - mean) * rs * g[lane + 64] + bta[lane + 64]);
}

// ---------------------------------------------------------------------------
// loss: grid (B, 2).  y==0: softplus(-mean6(out_z . preds)); y==1: softplus(+mean6(out_z . neg_e))
// ---------------------------------------------------------------------------
__global__ __launch_bounds__(256)
void loss_kernel(const bf16* __restrict__ out_z, const bf16* __restrict__ preds,
                 const bf16* __restrict__ neg_e, float* __restrict__ out)
{
  const int b = blockIdx.x;
  const int which = blockIdx.y;
  __shared__ __align__(16) bf16 zo[128 * 128];
  __shared__ __align__(16) bf16 mt[128 * 128];
  const bf16* msrc = which ? neg_e : preds;
  const uint4* gz = (const uint4*)(out_z + (size_t)b * 16384);
  const uint4* gm = (const uint4*)(msrc + (size_t)b * 16384);
  for (int it = threadIdx.x; it < 2048; it += 256) {
    ((uint4*)zo)[it] = gz[it];
    ((uint4*)mt)[it] = gm[it];
  }
  __syncthreads();
  float local = 0.f;
  for (int it = threadIdx.x; it < 232; it += 256) {
    const int i = it >> 1;         // valid row 0..115
    const int sub = it & 1;        // group
    const int c0 = i + (sub ? 7 : 0);
    const bf16* zr = &zo[i * 128];
    float accv = 0.f;
    for (int jj = 0; jj < 6; jj++) {
      const bf16* mr = &mt[(c0 + jj) * 128];
      float d = 0.f;
#pragma unroll
      for (int dd = 0; dd < 128; dd++) d += b2f(zr[dd]) * b2f(mr[dd]);
      accv += d;
    }
    const float mean = accv * (1.f / 6.f);
    const float xin = which ? mean : -mean;
    local += fmaxf(xin, 0.f) + log1pf(expf(-fabsf(xin)));
  }
  local = wave_sum(local);
  if ((threadIdx.x & 63) == 0)
    atomicAdd(out, local * (1.f / 118784.f));
}

__global__ void zero_kernel(float* p) { p[0] = 0.f; }

// ---------------------------------------------------------------------------
extern "C" void kernel_launch(void* const* d_in, const int* in_sizes, int n_in,
                              void* d_out, int out_size, void* d_ws, size_t ws_size,
                              hipStream_t stream)
{
  (void)in_sizes; (void)n_in; (void)out_size; (void)ws_size;
  const int*   seq     = (const int*)  d_in[0];
  const int*   neg_idx = (const int*)  d_in[1];
  const float* embed_W = (const float*)d_in[2];
  const float* embed_g = (const float*)d_in[3];
  const float* embed_b = (const float*)d_in[4];
  const float* proj_W  = (const float*)d_in[5];
  const float* proj_b  = (const float*)d_in[6];
  const float* qkv_W   = (const float*)d_in[7];
  const float* qkv_b   = (const float*)d_in[8];
  const float* ao_W    = (const float*)d_in[9];
  const float* ao_b    = (const float*)d_in[10];
  const float* ln1_g   = (const float*)d_in[11];
  const float* ln1_b   = (const float*)d_in[12];
  const float* ff1_W   = (const float*)d_in[13];
  const float* ff1_b   = (const float*)d_in[14];
  const float* ff2_W   = (const float*)d_in[15];
  const float* ff2_b   = (const float*)d_in[16];
  const float* ln2_g   = (const float*)d_in[17];
  const float* ln2_b   = (const float*)d_in[18];
  const float* head_W  = (const float*)d_in[19];
  const float* head_b  = (const float*)d_in[20];
  const float* head_g  = (const float*)d_in[21];
  const float* head_bt = (const float*)d_in[22];
  const float* oemb_W  = (const float*)d_in[23];
  const float* oemb_g  = (const float*)d_in[24];
  const float* oemb_b  = (const float*)d_in[25];
  float* out = (float*)d_out;

  char* ws = (char*)d_ws;
  size_t off = 0;
  auto alloc = [&](size_t bytes) -> char* {
    char* p = ws + off;
    off += (bytes + 255) & ~(size_t)255;
    return p;
  };
  bf16* wt_qkv  = (bf16*)alloc((size_t)2304 * 768 * 2);
  bf16* wt_ao   = (bf16*)alloc((size_t)768 * 768 * 2);
  bf16* wt_ff1  = (bf16*)alloc((size_t)3072 * 768 * 2);
  bf16* wt_ff2  = (bf16*)alloc((size_t)768 * 3072 * 2);
  bf16* wt_proj = (bf16*)alloc((size_t)768 * 128 * 2);
  bf16* wt_head = (bf16*)alloc((size_t)128 * 768 * 2);
  bf16* zbuf    = (bf16*)alloc((size_t)M_TOK * 128 * 2);
  bf16* x       = (bf16*)alloc((size_t)M_TOK * 768 * 2);
  bf16* big     = (bf16*)alloc((size_t)M_TOK * 3072 * 2);  // qkv, then h
  bf16* ctx     = (bf16*)alloc((size_t)M_TOK * 768 * 2);
  bf16* ybuf    = (bf16*)alloc((size_t)M_TOK * 768 * 2);
  bf16* p0      = (bf16*)alloc((size_t)M_TOK * 128 * 2);
  bf16* preds   = (bf16*)alloc((size_t)M_TOK * 128 * 2);
  bf16* outz    = (bf16*)alloc((size_t)M_TOK * 128 * 2);
  bf16* nege    = (bf16*)alloc((size_t)M_TOK * 128 * 2);

  const dim3 tb(32, 8);

  convtrans<<<dim3(768 / 32, 128 / 32), tb, 0, stream>>>(proj_W, wt_proj, 128, 768);
  convtrans<<<dim3(128 / 32, 768 / 32), tb, 0, stream>>>(head_W, wt_head, 768, 128);

  gather_ln128<<<M_TOK / 4, 256, 0, stream>>>(seq, embed_W, embed_g, embed_b, zbuf);
  gemm_bt<<<dim3(768 / 128, M_TOK / 128), 256, 0, stream>>>(zbuf, wt_proj, proj_b, x,
                                                            M_TOK, 768, 128, 2);

  for (int l = 0; l < LAYERS_; ++l) {
    convtrans<<<dim3(2304 / 32, 768 / 32), tb, 0, stream>>>(qkv_W + (size_t)l * 768 * 2304, wt_qkv, 768, 2304);
    convtrans<<<dim3(768 / 32, 768 / 32), tb, 0, stream>>>(ao_W + (size_t)l * 768 * 768, wt_ao, 768, 768);
    convtrans<<<dim3(3072 / 32, 768 / 32), tb, 0, stream>>>(ff1_W + (size_t)l * 768 * 3072, wt_ff1, 768, 3072);
    convtrans<<<dim3(768 / 32, 3072 / 32), tb, 0, stream>>>(ff2_W + (size_t)l * 3072 * 768, wt_ff2, 3072, 768);

    gemm_bt<<<dim3(2304 / 128, M_TOK / 128), 256, 0, stream>>>(x, wt_qkv, qkv_b + l * 2304, big,
                                                               M_TOK, 2304, 768, 0);
    attn_kernel<<<B_ * HEADS_, 128, 0, stream>>>(big, ctx);
    gemm_bt<<<dim3(768 / 128, M_TOK / 128), 256, 0, stream>>>(ctx, wt_ao, ao_b + l * 768, ybuf,
                                                              M_TOK, 768, 768, 0);
    add_ln_kernel<<<M_TOK, 256, 0, stream>>>(x, ybuf, ln1_g + l * 768, ln1_b + l * 768, x);
    gemm_bt<<<dim3(3072 / 128, M_TOK / 128), 256, 0, stream>>>(x, wt_ff1, ff1_b + l * 3072, big,
                                                               M_TOK, 3072, 768, 1);
    gemm_bt<<<dim3(768 / 128, M_TOK / 128), 256, 0, stream>>>(big, wt_ff2, ff2_b + l * 768, ybuf,
                                                              M_TOK, 768, 3072, 0);
    add_ln_kernel<<<M_TOK, 256, 0, stream>>>(x, ybuf, ln2_g + l * 768, ln2_b + l * 768, x);
  }

  gemm_bt<<<dim3(1, M_TOK / 128), 256, 0, stream>>>(x, wt_head, head_b, p0, M_TOK, 128, 768, 0);
  ln128_bf16<<<M_TOK / 4, 256, 0, stream>>>(p0, head_g, head_bt, preds);
  gather_ln128<<<M_TOK / 4, 256, 0, stream>>>(seq, oemb_W, oemb_g, oemb_b, outz);
  gather_ln128<<<M_TOK / 4, 256, 0, stream>>>(neg_idx, oemb_W, oemb_g, oemb_b, nege);
  zero_kernel<<<1, 1, 0, stream>>>(out);
  loss_kernel<<<dim3(B_, 2), 256, 0, stream>>>(outz, preds, nege, out);
}